// Round 3
// baseline (4932.350 us; speedup 1.0000x reference)
//
#include <hip/hip_runtime.h>
#include <hip/hip_bf16.h>
#include <stdint.h>

typedef __attribute__((ext_vector_type(8))) short bf16x8;
typedef __attribute__((ext_vector_type(4))) float floatx4;

#define DEV __device__ __forceinline__

DEV void gl_lds16(const void* g, void* lds) {
    __builtin_amdgcn_global_load_lds(
        (const __attribute__((address_space(1))) unsigned int*)g,
        (__attribute__((address_space(3))) unsigned int*)lds, 16, 0, 0);
}

struct __align__(8) bf4 { __hip_bfloat16 h[4]; };

// ===========================================================================
// STAGE 1 (direct-register, no LDS, no barriers):
//   P[kp][n] = (A[im[k,p]] @ W[k])[n]
// MFMA A/B fragments are 16 contiguous bytes of the gathered A row / BT row
// (lane lm,lq holds elements [k = lq*8 .. +8) of row lm) -> load them with
// plain global_load_dwordx4 straight into registers. Register ping-pong over
// K-steps lets the compiler emit a fine-grained vmcnt pipeline (no barrier
// drain -- the thing the LDS-staged structure could not express).
// P row layout lane-permuted (col = nt*16+lm stored at pos lm*4+nt);
// stage 2 undoes it at the final write.
// ===========================================================================
template <int KSTEPS>
__global__ __launch_bounds__(256) void spconv_stage1(
    const __hip_bfloat16* __restrict__ A, const __hip_bfloat16* __restrict__ BT,
    const int* __restrict__ in_map, __hip_bfloat16* __restrict__ P, int M) {
    constexpr int K = KSTEPS * 32;
    const int tid = threadIdx.x;
    const int w = tid >> 6;
    const int l = tid & 63;
    const int wm = w & 1, wn = w >> 1;
    const int lm = l & 15, lq = l >> 4;
    const int kz = blockIdx.z;
    const int m0 = blockIdx.x * 128;
    const int n0 = blockIdx.y * 128;

    const int* im = in_map + (size_t)kz * M;

    const __hip_bfloat16* arow[4];
#pragma unroll
    for (int mt = 0; mt < 4; mt++) {
        int p = m0 + wm * 64 + mt * 16 + lm;
        if (p > M - 1) p = M - 1;
        arow[mt] = A + (size_t)im[p] * K + lq * 8;
    }
    const __hip_bfloat16* brow[4];
#pragma unroll
    for (int nt = 0; nt < 4; nt++)
        brow[nt] = BT + ((size_t)kz * 256 + n0 + wn * 64 + nt * 16 + lm) * (size_t)K + lq * 8;

    floatx4 acc[4][4];
#pragma unroll
    for (int i = 0; i < 4; i++)
#pragma unroll
        for (int j = 0; j < 4; j++) acc[i][j] = (floatx4)0.0f;

    bf16x8 af[2][4], bf[2][4];
#pragma unroll
    for (int i = 0; i < 4; i++) {
        af[0][i] = *(const bf16x8*)(arow[i]);
        bf[0][i] = *(const bf16x8*)(brow[i]);
    }

#pragma unroll
    for (int ks = 0; ks < KSTEPS; ks++) {
        const int cur = ks & 1, nxt = cur ^ 1;
        if (ks + 1 < KSTEPS) {
#pragma unroll
            for (int i = 0; i < 4; i++) {
                af[nxt][i] = *(const bf16x8*)(arow[i] + (ks + 1) * 32);
                bf[nxt][i] = *(const bf16x8*)(brow[i] + (ks + 1) * 32);
            }
        }
#pragma unroll
        for (int mt = 0; mt < 4; mt++)
#pragma unroll
            for (int nt = 0; nt < 4; nt++)
                acc[mt][nt] = __builtin_amdgcn_mfma_f32_16x16x32_bf16(
                    af[cur][mt], bf[cur][nt], acc[mt][nt], 0, 0, 0);
    }

    // epilogue: coalesced permuted bf16 stores (C/D layout: col=lane&15,
    // row=(lane>>4)*4+reg -- m89/m91-verified)
    __hip_bfloat16* pbase = P + (size_t)kz * M * 256 + n0 + wn * 64 + lm * 4;
#pragma unroll
    for (int mt = 0; mt < 4; mt++) {
        const int rowb = wm * 64 + mt * 16 + lq * 4;
#pragma unroll
        for (int r = 0; r < 4; r++) {
            const int pair = m0 + rowb + r;
            if (pair < M) {
                bf4 o;
#pragma unroll
                for (int nt = 0; nt < 4; nt++)
                    o.h[nt] = __float2bfloat16(acc[mt][nt][r]);
                *(bf4*)(pbase + (size_t)pair * 256) = o;
            }
        }
    }
}

// ===========================================================================
// STAGE 2: one wave per output row; 4-way unrolled branch-free CSR gather
// (predicated address + 0/1 weight) so 4 independent P-row loads are in
// flight. fin_mode: 0 = f32 partial (permuted), 1 = conv_t final (bf16 into
// x_bf), 2 = conv_c final (f32 into out).
// ===========================================================================
__global__ void stage2_kernel(const unsigned* __restrict__ start,
                              const unsigned* __restrict__ entries,
                              const __hip_bfloat16* __restrict__ P,
                              int kp_lo, int kp_hi,
                              float* __restrict__ partial, int init, int fin_mode,
                              __hip_bfloat16* __restrict__ xbf,
                              float* __restrict__ outp,
                              const float* __restrict__ g, const float* __restrict__ b,
                              const float* __restrict__ mu, const float* __restrict__ var) {
    const int tid = threadIdx.x;
    const int r = blockIdx.x * 4 + (tid >> 6);  // grid sized exactly: r < 200000
    const int l = tid & 63;
    const int pos0 = l * 4;

    float acc[4];
    if (init) {
        acc[0] = acc[1] = acc[2] = acc[3] = 0.0f;
    } else {
        const float4 t = *(const float4*)(partial + (size_t)r * 256 + pos0);
        acc[0] = t.x; acc[1] = t.y; acc[2] = t.z; acc[3] = t.w;
    }

    const unsigned s0 = start[r], s1 = start[r + 1];
    const unsigned cnt = s1 - s0;
    for (unsigned i = 0; i < cnt; i += 4) {
        const bf4* addr[4];
        float wgt[4];
#pragma unroll
        for (int j = 0; j < 4; j++) {
            unsigned idx = i + j;
            unsigned ee = s0 + ((idx < cnt) ? idx : (cnt - 1));
            const int kp = (int)entries[ee];
            const bool ok = (idx < cnt) & (kp >= kp_lo) & (kp < kp_hi);
            addr[j] = (const bf4*)(P + (ok ? (size_t)(kp - kp_lo) * 256 : 0) + pos0);
            wgt[j] = ok ? 1.0f : 0.0f;
        }
        bf4 v[4];
#pragma unroll
        for (int j = 0; j < 4; j++) v[j] = *addr[j];
#pragma unroll
        for (int j = 0; j < 4; j++)
#pragma unroll
            for (int c = 0; c < 4; c++)
                acc[c] = fmaf(wgt[j], __bfloat162float(v[j].h[c]), acc[c]);
    }

    if (fin_mode == 0) {
        *(float4*)(partial + (size_t)r * 256 + pos0) =
            make_float4(acc[0], acc[1], acc[2], acc[3]);
    } else {
        const int chunk = l >> 4, lm = l & 15;
#pragma unroll
        for (int j = 0; j < 4; j++) {
            const int c = chunk * 64 + j * 16 + lm;  // un-permute: pos -> col
            const float s = g[c] * rsqrtf(var[c] + 1e-5f);
            const float val = fmaxf((acc[j] - mu[c]) * s + b[c], 0.0f);
            if (fin_mode == 1)
                xbf[(size_t)r * 384 + c] = __float2bfloat16(val);
            else
                outp[(size_t)r * 256 + c] = val;
        }
    }
}

// =============================== CSR build =================================
__global__ void hist_kernel(const int* __restrict__ om, int n,
                            unsigned* __restrict__ cnt) {
    int stride = gridDim.x * blockDim.x;
    for (int i = blockIdx.x * blockDim.x + threadIdx.x; i < n; i += stride)
        atomicAdd(&cnt[om[i]], 1u);
}

__global__ void scan1_kernel(const unsigned* __restrict__ cnt,
                             unsigned* __restrict__ start,
                             unsigned* __restrict__ bsum, int N) {
    __shared__ unsigned sums[256];
    const int t = threadIdx.x;
    const int base = blockIdx.x * 1024 + t * 4;
    unsigned v[4];
#pragma unroll
    for (int j = 0; j < 4; j++) v[j] = (base + j < N) ? cnt[base + j] : 0u;
    const unsigned T = v[0] + v[1] + v[2] + v[3];
    sums[t] = T;
    __syncthreads();
    for (int off = 1; off < 256; off <<= 1) {
        unsigned x = (t >= off) ? sums[t - off] : 0u;
        __syncthreads();
        sums[t] += x;
        __syncthreads();
    }
    unsigned run = sums[t] - T;  // exclusive
#pragma unroll
    for (int j = 0; j < 4; j++) {
        if (base + j < N) start[base + j] = run;
        run += v[j];
    }
    if (t == 255) bsum[blockIdx.x] = sums[255];
}

__global__ void scan2_kernel(unsigned* bsum, int nb) {
    __shared__ unsigned sums[256];
    const int t = threadIdx.x;
    const unsigned v = (t < nb) ? bsum[t] : 0u;
    sums[t] = v;
    __syncthreads();
    for (int off = 1; off < 256; off <<= 1) {
        unsigned x = (t >= off) ? sums[t - off] : 0u;
        __syncthreads();
        sums[t] += x;
        __syncthreads();
    }
    if (t < nb) bsum[t] = sums[t] - v;  // exclusive
}

__global__ void scan3_kernel(unsigned* __restrict__ start,
                             const unsigned* __restrict__ bsum,
                             unsigned* __restrict__ cursor, int N, unsigned total) {
    const int t = threadIdx.x;
    const int base = blockIdx.x * 1024 + t * 4;
    const unsigned add = bsum[blockIdx.x];
#pragma unroll
    for (int j = 0; j < 4; j++) {
        const int i = base + j;
        if (i < N) {
            const unsigned s = start[i] + add;
            start[i] = s;
            cursor[i] = s;
        }
    }
    if (blockIdx.x == gridDim.x - 1 && t == 255) start[N] = total;
}

__global__ void scatter_kernel(const int* __restrict__ om, int n,
                               unsigned* __restrict__ cursor,
                               unsigned* __restrict__ entries) {
    int stride = gridDim.x * blockDim.x;
    for (int i = blockIdx.x * blockDim.x + threadIdx.x; i < n; i += stride) {
        unsigned pos = atomicAdd(&cursor[om[i]], 1u);
        entries[pos] = (unsigned)i;  // i == k*M + p (maps are [K][M] flat)
    }
}

// ============================ elementwise prep =============================
__global__ void cast_bf16_kernel(const float* __restrict__ in,
                                 __hip_bfloat16* __restrict__ out, int n4) {
    int stride = gridDim.x * blockDim.x;
    for (int i = blockIdx.x * blockDim.x + threadIdx.x; i < n4; i += stride) {
        float4 v = ((const float4*)in)[i];
        bf4 o;
        o.h[0] = __float2bfloat16(v.x);
        o.h[1] = __float2bfloat16(v.y);
        o.h[2] = __float2bfloat16(v.z);
        o.h[3] = __float2bfloat16(v.w);
        ((bf4*)out)[i] = o;
    }
}

__global__ void transpose_cast_w(const float* __restrict__ W,
                                 __hip_bfloat16* __restrict__ WT, int Koff,
                                 int Cin, int Cout) {
    int total = Koff * Cin * Cout;
    int stride = gridDim.x * blockDim.x;
    for (int i = blockIdx.x * blockDim.x + threadIdx.x; i < total; i += stride) {
        int k = i / (Cin * Cout);
        int r = i - k * (Cin * Cout);
        int n = r / Cin;
        int kk = r - n * Cin;
        WT[i] = __float2bfloat16(W[((size_t)k * Cin + kk) * Cout + n]);
    }
}

__global__ void concat_b_kernel(const float* __restrict__ fb,
                                __hip_bfloat16* __restrict__ X) {
    const int total = 200000 * 32;
    int stride = gridDim.x * blockDim.x;
    for (int i = blockIdx.x * blockDim.x + threadIdx.x; i < total; i += stride) {
        int row = i >> 5;
        int c4 = (i & 31) * 4;
        float4 t = *(const float4*)(fb + (size_t)row * 128 + c4);
        bf4 o;
        o.h[0] = __float2bfloat16(t.x);
        o.h[1] = __float2bfloat16(t.y);
        o.h[2] = __float2bfloat16(t.z);
        o.h[3] = __float2bfloat16(t.w);
        *(bf4*)(X + (size_t)row * 384 + 256 + c4) = o;
    }
}

// =================== fallback path (atomic scatter, proven) ================
template <int KSTEPS>
__global__ __launch_bounds__(256) void spconv_atomic(
    const __hip_bfloat16* __restrict__ A, const __hip_bfloat16* __restrict__ BT,
    const int* __restrict__ in_map, const int* __restrict__ out_map,
    float* __restrict__ Out, int M) {
    constexpr int K = KSTEPS * 32;
    __shared__ __align__(16) char Abuf[8192];
    __shared__ __align__(16) char Bbuf[8192];
    __shared__ int om_s[128];

    const int tid = threadIdx.x;
    const int w = tid >> 6;
    const int l = tid & 63;
    const int koff = blockIdx.z;
    const int m0 = blockIdx.x * 128;
    const int n0 = blockIdx.y * 128;

    const int* im = in_map + (size_t)koff * M;
    const int* om = out_map + (size_t)koff * M;

    if (tid < 128) {
        int p = m0 + tid;
        om_s[tid] = (p < M) ? om[p] : -1;
    }

    const int rS = (w & 1) * 64 + l;
    int prow = m0 + rS;
    if (prow > M - 1) prow = M - 1;
    const __hip_bfloat16* a_row = A + (size_t)im[prow] * K;
    const __hip_bfloat16* b_row = BT + ((size_t)koff * 256 + n0 + rS) * (size_t)K;
    const int q0 = w >> 1;

    char* Al = Abuf + w * 1024 + l * 16;
    char* Bl = Bbuf + w * 1024 + l * 16;

    floatx4 acc[4][4];
#pragma unroll
    for (int i = 0; i < 4; i++)
#pragma unroll
        for (int j = 0; j < 4; j++) acc[i][j] = (floatx4)0.0f;

    const int wm = w & 1, wn = w >> 1;
    const int lm = l & 15, lq = l >> 4;

    for (int ks = 0; ks < KSTEPS; ks++) {
        const int kb = ks * 32;
        gl_lds16(a_row + kb + q0 * 8, Al);
        gl_lds16(a_row + kb + (q0 + 2) * 8, Al + 4096);
        gl_lds16(b_row + kb + q0 * 8, Bl);
        gl_lds16(b_row + kb + (q0 + 2) * 8, Bl + 4096);
        __syncthreads();

        bf16x8 af[4], bf[4];
#pragma unroll
        for (int mt = 0; mt < 4; mt++)
            af[mt] = *(const bf16x8*)(Abuf + lq * 2048 + (wm * 64 + mt * 16 + lm) * 16);
#pragma unroll
        for (int nt = 0; nt < 4; nt++)
            bf[nt] = *(const bf16x8*)(Bbuf + lq * 2048 + (wn * 64 + nt * 16 + lm) * 16);

#pragma unroll
        for (int mt = 0; mt < 4; mt++)
#pragma unroll
            for (int nt = 0; nt < 4; nt++)
                acc[mt][nt] = __builtin_amdgcn_mfma_f32_16x16x32_bf16(
                    af[mt], bf[nt], acc[mt][nt], 0, 0, 0);

        __syncthreads();
    }

#pragma unroll
    for (int mt = 0; mt < 4; mt++) {
        const int mbase = wm * 64 + mt * 16 + lq * 4;
#pragma unroll
        for (int r = 0; r < 4; r++) {
            const int orow = om_s[mbase + r];
            if (orow >= 0) {
                float* dst = Out + (size_t)orow * 256 + n0 + wn * 64 + lm;
#pragma unroll
                for (int nt = 0; nt < 4; nt++)
                    unsafeAtomicAdd(dst + nt * 16, acc[mt][nt][r]);
            }
        }
    }
}

__global__ void bn_concat_kernel(const float* __restrict__ xa,
                                 const float* __restrict__ fb,
                                 const float* __restrict__ g,
                                 const float* __restrict__ b,
                                 const float* __restrict__ mu,
                                 const float* __restrict__ var,
                                 __hip_bfloat16* __restrict__ X) {
    const int total = 200000 * 96;
    int stride = gridDim.x * blockDim.x;
    for (int i = blockIdx.x * blockDim.x + threadIdx.x; i < total; i += stride) {
        int row = i / 96;
        int c4 = (i - row * 96) * 4;
        float v[4];
        if (c4 < 256) {
            float4 t = *(const float4*)(xa + (size_t)row * 256 + c4);
            v[0] = t.x; v[1] = t.y; v[2] = t.z; v[3] = t.w;
#pragma unroll
            for (int j = 0; j < 4; j++) {
                int c = c4 + j;
                float s = g[c] * rsqrtf(var[c] + 1e-5f);
                v[j] = fmaxf((v[j] - mu[c]) * s + b[c], 0.0f);
            }
        } else {
            float4 t = *(const float4*)(fb + (size_t)row * 128 + (c4 - 256));
            v[0] = t.x; v[1] = t.y; v[2] = t.z; v[3] = t.w;
        }
        bf4 o;
#pragma unroll
        for (int j = 0; j < 4; j++) o.h[j] = __float2bfloat16(v[j]);
        *(bf4*)(X + (size_t)row * 384 + c4) = o;
    }
}

__global__ void bn_out_kernel(float* __restrict__ out, const float* __restrict__ g,
                              const float* __restrict__ b,
                              const float* __restrict__ mu,
                              const float* __restrict__ var) {
    const int total = 200000 * 64;
    int stride = gridDim.x * blockDim.x;
    for (int i = blockIdx.x * blockDim.x + threadIdx.x; i < total; i += stride) {
        int c4 = (i & 63) * 4;
        float4 t = ((const float4*)out)[i];
        float v[4] = {t.x, t.y, t.z, t.w};
#pragma unroll
        for (int j = 0; j < 4; j++) {
            int c = c4 + j;
            float s = g[c] * rsqrtf(var[c] + 1e-5f);
            v[j] = fmaxf((v[j] - mu[c]) * s + b[c], 0.0f);
        }
        ((float4*)out)[i] = make_float4(v[0], v[1], v[2], v[3]);
    }
}

// ===========================================================================
extern "C" void kernel_launch(void* const* d_in, const int* in_sizes, int n_in,
                              void* d_out, int out_size, void* d_ws,
                              size_t ws_size, hipStream_t stream) {
    const float* feats_a = (const float*)d_in[0];
    const float* feats_b = (const float*)d_in[1];
    const float* W_t = (const float*)d_in[2];
    const float* bn_t_gamma = (const float*)d_in[3];
    const float* bn_t_beta = (const float*)d_in[4];
    const float* bn_t_mean = (const float*)d_in[5];
    const float* bn_t_var = (const float*)d_in[6];
    const float* W_c = (const float*)d_in[7];
    const float* bn_c_gamma = (const float*)d_in[8];
    const float* bn_c_beta = (const float*)d_in[9];
    const float* bn_c_mean = (const float*)d_in[10];
    const float* bn_c_var = (const float*)d_in[11];
    const int* in_map_t = (const int*)d_in[12];
    const int* out_map_t = (const int*)d_in[13];
    const int* in_map_c = (const int*)d_in[14];
    const int* out_map_c = (const int*)d_in[15];
    float* out = (float*)d_out;

    // ---- workspace layout (all 256B aligned) ----
    char* ws = (char*)d_ws;
    __hip_bfloat16* a_bf = (__hip_bfloat16*)(ws + 0);            // 25,600,000
    __hip_bfloat16* wtT  = (__hip_bfloat16*)(ws + 25600000);     //  1,048,576
    __hip_bfloat16* wcT  = (__hip_bfloat16*)(ws + 26648576);     //  5,308,416
    __hip_bfloat16* x_bf = (__hip_bfloat16*)(ws + 31956992);     // 153,600,000
    unsigned* cnt   = (unsigned*)(ws + 185556992);               //    800,000
    unsigned* start = (unsigned*)(ws + 186356992);               //    800,256
    unsigned* bsum  = (unsigned*)(ws + 187157248);               //      1,024
    unsigned* cur   = (unsigned*)(ws + 187158272);               //    800,000
    unsigned* ent   = (unsigned*)(ws + 187958272);               // 12,960,000
    __hip_bfloat16* P = (__hip_bfloat16*)(ws + 200918272);
    const size_t p_avail = (ws_size > 200918272u) ? ws_size - 200918272u : 0;
    int g_c = (int)(p_avail / 61440000ull); if (g_c > 27) g_c = 27;
    int g_t = (int)(p_avail / 51200000ull); if (g_t > 8) g_t = 8;
    const bool ts_t = (g_t >= 4);
    const bool ts_c = (g_c >= 5);

    cast_bf16_kernel<<<512, 256, 0, stream>>>(feats_a, a_bf, 50000 * 256 / 4);
    transpose_cast_w<<<512, 256, 0, stream>>>(W_t, wtT, 8, 256, 256);
    transpose_cast_w<<<512, 256, 0, stream>>>(W_c, wcT, 27, 384, 256);

    // ---------------- conv_t ----------------
    if (ts_t) {
        concat_b_kernel<<<2048, 256, 0, stream>>>(feats_b, x_bf);
        hipMemsetAsync(cnt, 0, 800000, stream);
        hist_kernel<<<1024, 256, 0, stream>>>(out_map_t, 800000, cnt);
        scan1_kernel<<<196, 256, 0, stream>>>(cnt, start, bsum, 200000);
        scan2_kernel<<<1, 256, 0, stream>>>(bsum, 196);
        scan3_kernel<<<196, 256, 0, stream>>>(start, bsum, cur, 200000, 800000);
        scatter_kernel<<<1024, 256, 0, stream>>>(out_map_t, 800000, cur, ent);
        for (int q0 = 0; q0 < 8; q0 += g_t) {
            const int q1 = (q0 + g_t < 8) ? q0 + g_t : 8;
            dim3 gs(782, 2, q1 - q0);
            spconv_stage1<8><<<gs, 256, 0, stream>>>(
                a_bf, wtT + (size_t)q0 * 256 * 256, in_map_t + (size_t)q0 * 100000,
                P, 100000);
            stage2_kernel<<<50000, 256, 0, stream>>>(
                start, ent, P, q0 * 100000, q1 * 100000, out, (q0 == 0) ? 1 : 0,
                (q1 == 8) ? 1 : 0, x_bf, out, bn_t_gamma, bn_t_beta, bn_t_mean,
                bn_t_var);
        }
    } else {
        hipMemsetAsync(d_out, 0, (size_t)out_size * sizeof(float), stream);
        dim3 g1(782, 2, 8);
        spconv_atomic<8><<<g1, 256, 0, stream>>>(a_bf, wtT, in_map_t, out_map_t,
                                                 out, 100000);
        bn_concat_kernel<<<2048, 256, 0, stream>>>(out, feats_b, bn_t_gamma,
                                                   bn_t_beta, bn_t_mean, bn_t_var,
                                                   x_bf);
    }

    // ---------------- conv_c ----------------
    if (ts_c) {
        hipMemsetAsync(cnt, 0, 800000, stream);
        hist_kernel<<<1024, 256, 0, stream>>>(out_map_c, 3240000, cnt);
        scan1_kernel<<<196, 256, 0, stream>>>(cnt, start, bsum, 200000);
        scan2_kernel<<<1, 256, 0, stream>>>(bsum, 196);
        scan3_kernel<<<196, 256, 0, stream>>>(start, bsum, cur, 200000, 3240000);
        scatter_kernel<<<1024, 256, 0, stream>>>(out_map_c, 3240000, cur, ent);
        for (int q0 = 0; q0 < 27; q0 += g_c) {
            const int q1 = (q0 + g_c < 27) ? q0 + g_c : 27;
            dim3 gs(938, 2, q1 - q0);
            spconv_stage1<12><<<gs, 256, 0, stream>>>(
                x_bf, wcT + (size_t)q0 * 256 * 384, in_map_c + (size_t)q0 * 120000,
                P, 120000);
            stage2_kernel<<<50000, 256, 0, stream>>>(
                start, ent, P, q0 * 120000, q1 * 120000, out, (q0 == 0) ? 1 : 0,
                (q1 == 27) ? 2 : 0, x_bf, out, bn_c_gamma, bn_c_beta, bn_c_mean,
                bn_c_var);
        }
    } else {
        hipMemsetAsync(d_out, 0, (size_t)out_size * sizeof(float), stream);
        dim3 g2(938, 2, 27);
        spconv_atomic<12><<<g2, 256, 0, stream>>>(x_bf, wcT, in_map_c, out_map_c,
                                                  out, 120000);
        bn_out_kernel<<<2048, 256, 0, stream>>>(out, bn_c_gamma, bn_c_beta,
                                                bn_c_mean, bn_c_var);
    }
}

// Round 4
// 4060.450 us; speedup vs baseline: 1.2147x; 1.2147x over previous
//
#include <hip/hip_runtime.h>
#include <hip/hip_bf16.h>
#include <stdint.h>
#include <string.h>

typedef __attribute__((ext_vector_type(8))) short bf16x8;
typedef __attribute__((ext_vector_type(4))) float floatx4;

#define DEV __device__ __forceinline__

DEV void gl_lds16(const void* g, void* lds) {
    __builtin_amdgcn_global_load_lds(
        (const __attribute__((address_space(1))) unsigned int*)g,
        (__attribute__((address_space(3))) unsigned int*)lds, 16, 0, 0);
}

struct __align__(8) bf4 { __hip_bfloat16 h[4]; };

// ===========================================================================
// STAGE 1 (full-row LDS staging, ONE barrier per block):
//   P[kp][n] = (A[im[k,p]] @ W[k])[n]
// BM=64 pairs x BN=256 (full Cout), 4 waves, each wave 64x64.
// The whole gathered A-tile (64 rows x K) is staged with KSTEPS independent
// global_load_lds issues -> ONE vmcnt drain per block (vs one per K-step).
// LDS quad-major: 16B-quad q (k-range [q*8,q*8+8)) of row r at (q*64+r)*16.
// Staging round j, wave w covers quad q=j*4+w for rows 0..63 (lane=row):
// dest = uniform base + lane*16 (m104-legal), source = per-lane gather.
// Fragment ds_read_b128 by 16 lanes strides 16B -> 2-way bank alias (free).
// B fragments are direct global->register loads (L2-resident), 2-step
// ping-pong. P written lane-permuted (col=nt*16+lm at pos lm*4+nt) with
// nontemporal stores; stage 2 un-permutes at its final write.
// ===========================================================================
template <int KSTEPS>
__global__ __launch_bounds__(256, 3) void spconv_stage1(
    const __hip_bfloat16* __restrict__ A, const __hip_bfloat16* __restrict__ BT,
    const int* __restrict__ in_map, __hip_bfloat16* __restrict__ P, int M) {
    constexpr int K = KSTEPS * 32;
    __shared__ __align__(16) char Abuf[KSTEPS * 4096];

    const int tid = threadIdx.x;
    const int w = tid >> 6;
    const int l = tid & 63;
    const int lm = l & 15, lq = l >> 4;
    const int kz = blockIdx.z;
    const int m0 = blockIdx.x * 64;

    const int* im = in_map + (size_t)kz * M;
    int p = m0 + l;
    if (p > M - 1) p = M - 1;
    const __hip_bfloat16* asrc = A + (size_t)im[p] * K + w * 8;

    // stage whole A tile: KSTEPS issues, all in flight simultaneously
#pragma unroll
    for (int j = 0; j < KSTEPS; j++)
        gl_lds16(asrc + j * 32, Abuf + ((j * 4 + w) * 64 + l) * 16);

    const __hip_bfloat16* brow[4];
#pragma unroll
    for (int nt = 0; nt < 4; nt++)
        brow[nt] = BT + ((size_t)kz * 256 + w * 64 + nt * 16 + lm) * (size_t)K + lq * 8;

    bf16x8 bfr[2][4];
#pragma unroll
    for (int nt = 0; nt < 4; nt++) bfr[0][nt] = *(const bf16x8*)(brow[nt]);

    floatx4 acc[4][4];
#pragma unroll
    for (int i = 0; i < 4; i++)
#pragma unroll
        for (int j = 0; j < 4; j++) acc[i][j] = (floatx4)0.0f;

    __syncthreads();  // single vmcnt drain: A tile (and B step-0) resident

#pragma unroll
    for (int ks = 0; ks < KSTEPS; ks++) {
        const int cur = ks & 1, nxt = cur ^ 1;
        if (ks + 1 < KSTEPS) {
#pragma unroll
            for (int nt = 0; nt < 4; nt++)
                bfr[nxt][nt] = *(const bf16x8*)(brow[nt] + (ks + 1) * 32);
        }
        bf16x8 af[4];
#pragma unroll
        for (int mt = 0; mt < 4; mt++)
            af[mt] = *(const bf16x8*)(Abuf +
                                      (((ks * 4 + lq) * 64) + mt * 16 + lm) * 16);
#pragma unroll
        for (int mt = 0; mt < 4; mt++)
#pragma unroll
            for (int nt = 0; nt < 4; nt++)
                acc[mt][nt] = __builtin_amdgcn_mfma_f32_16x16x32_bf16(
                    af[mt], bfr[cur][nt], acc[mt][nt], 0, 0, 0);
    }

    // epilogue: C/D layout col=lane&15, row=(lane>>4)*4+reg (m89/m91-verified)
    __hip_bfloat16* pbase = P + (size_t)kz * M * 256 + w * 64 + lm * 4;
#pragma unroll
    for (int mt = 0; mt < 4; mt++) {
        const int rowb = mt * 16 + lq * 4;
#pragma unroll
        for (int r = 0; r < 4; r++) {
            const int pair = m0 + rowb + r;
            if (pair < M) {
                bf4 o;
#pragma unroll
                for (int nt = 0; nt < 4; nt++)
                    o.h[nt] = __float2bfloat16(acc[mt][nt][r]);
                uint64_t u;
                memcpy(&u, &o, 8);
                __builtin_nontemporal_store(
                    u, (uint64_t*)(pbase + (size_t)pair * 256));
            }
        }
    }
}

// ===========================================================================
// STAGE 2: one wave per output row; 8-way unrolled branch-free CSR gather
// (predicated address + 0/1 weight -> 8 independent P-row loads in flight).
// fin_mode: 0 = f32 partial (permuted), 1 = conv_t final (bf16 into x_bf),
//           2 = conv_c final (f32 into out).
// ===========================================================================
__global__ void stage2_kernel(const unsigned* __restrict__ start,
                              const unsigned* __restrict__ entries,
                              const __hip_bfloat16* __restrict__ P,
                              int kp_lo, int kp_hi,
                              float* __restrict__ partial, int init, int fin_mode,
                              __hip_bfloat16* __restrict__ xbf,
                              float* __restrict__ outp,
                              const float* __restrict__ g, const float* __restrict__ b,
                              const float* __restrict__ mu, const float* __restrict__ var) {
    const int tid = threadIdx.x;
    const int r = blockIdx.x * 4 + (tid >> 6);  // grid sized exactly: r < 200000
    const int l = tid & 63;
    const int pos0 = l * 4;

    float acc[4];
    if (init) {
        acc[0] = acc[1] = acc[2] = acc[3] = 0.0f;
    } else {
        const float4 t = *(const float4*)(partial + (size_t)r * 256 + pos0);
        acc[0] = t.x; acc[1] = t.y; acc[2] = t.z; acc[3] = t.w;
    }

    const unsigned s0 = start[r], s1 = start[r + 1];
    const unsigned cnt = s1 - s0;
    for (unsigned i = 0; i < cnt; i += 8) {
        const uint64_t* addr[8];
        float wgt[8];
#pragma unroll
        for (int j = 0; j < 8; j++) {
            unsigned idx = i + j;
            unsigned ee = s0 + ((idx < cnt) ? idx : (cnt - 1));
            const int kp = (int)entries[ee];
            const bool ok = (idx < cnt) & (kp >= kp_lo) & (kp < kp_hi);
            addr[j] = (const uint64_t*)(P + (ok ? (size_t)(kp - kp_lo) * 256 : 0) + pos0);
            wgt[j] = ok ? 1.0f : 0.0f;
        }
        uint64_t uv[8];
#pragma unroll
        for (int j = 0; j < 8; j++) uv[j] = __builtin_nontemporal_load(addr[j]);
#pragma unroll
        for (int j = 0; j < 8; j++) {
            bf4 v;
            memcpy(&v, &uv[j], 8);
#pragma unroll
            for (int c = 0; c < 4; c++)
                acc[c] = fmaf(wgt[j], __bfloat162float(v.h[c]), acc[c]);
        }
    }

    if (fin_mode == 0) {
        *(float4*)(partial + (size_t)r * 256 + pos0) =
            make_float4(acc[0], acc[1], acc[2], acc[3]);
    } else {
        const int chunk = l >> 4, lm = l & 15;
#pragma unroll
        for (int j = 0; j < 4; j++) {
            const int c = chunk * 64 + j * 16 + lm;  // un-permute: pos -> col
            const float s = g[c] * rsqrtf(var[c] + 1e-5f);
            const float val = fmaxf((acc[j] - mu[c]) * s + b[c], 0.0f);
            if (fin_mode == 1)
                xbf[(size_t)r * 384 + c] = __float2bfloat16(val);
            else
                outp[(size_t)r * 256 + c] = val;
        }
    }
}

// =============================== CSR build =================================
__global__ void hist_kernel(const int* __restrict__ om, int n,
                            unsigned* __restrict__ cnt) {
    int stride = gridDim.x * blockDim.x;
    for (int i = blockIdx.x * blockDim.x + threadIdx.x; i < n; i += stride)
        atomicAdd(&cnt[om[i]], 1u);
}

__global__ void scan1_kernel(const unsigned* __restrict__ cnt,
                             unsigned* __restrict__ start,
                             unsigned* __restrict__ bsum, int N) {
    __shared__ unsigned sums[256];
    const int t = threadIdx.x;
    const int base = blockIdx.x * 1024 + t * 4;
    unsigned v[4];
#pragma unroll
    for (int j = 0; j < 4; j++) v[j] = (base + j < N) ? cnt[base + j] : 0u;
    const unsigned T = v[0] + v[1] + v[2] + v[3];
    sums[t] = T;
    __syncthreads();
    for (int off = 1; off < 256; off <<= 1) {
        unsigned x = (t >= off) ? sums[t - off] : 0u;
        __syncthreads();
        sums[t] += x;
        __syncthreads();
    }
    unsigned run = sums[t] - T;  // exclusive
#pragma unroll
    for (int j = 0; j < 4; j++) {
        if (base + j < N) start[base + j] = run;
        run += v[j];
    }
    if (t == 255) bsum[blockIdx.x] = sums[255];
}

__global__ void scan2_kernel(unsigned* bsum, int nb) {
    __shared__ unsigned sums[256];
    const int t = threadIdx.x;
    const unsigned v = (t < nb) ? bsum[t] : 0u;
    sums[t] = v;
    __syncthreads();
    for (int off = 1; off < 256; off <<= 1) {
        unsigned x = (t >= off) ? sums[t - off] : 0u;
        __syncthreads();
        sums[t] += x;
        __syncthreads();
    }
    if (t < nb) bsum[t] = sums[t] - v;  // exclusive
}

__global__ void scan3_kernel(unsigned* __restrict__ start,
                             const unsigned* __restrict__ bsum,
                             unsigned* __restrict__ cursor, int N, unsigned total) {
    const int t = threadIdx.x;
    const int base = blockIdx.x * 1024 + t * 4;
    const unsigned add = bsum[blockIdx.x];
#pragma unroll
    for (int j = 0; j < 4; j++) {
        const int i = base + j;
        if (i < N) {
            const unsigned s = start[i] + add;
            start[i] = s;
            cursor[i] = s;
        }
    }
    if (blockIdx.x == gridDim.x - 1 && t == 255) start[N] = total;
}

__global__ void scatter_kernel(const int* __restrict__ om, int n,
                               unsigned* __restrict__ cursor,
                               unsigned* __restrict__ entries) {
    int stride = gridDim.x * blockDim.x;
    for (int i = blockIdx.x * blockDim.x + threadIdx.x; i < n; i += stride) {
        unsigned pos = atomicAdd(&cursor[om[i]], 1u);
        entries[pos] = (unsigned)i;  // i == k*M + p (maps are [K][M] flat)
    }
}

// ============================ elementwise prep =============================
__global__ void cast_bf16_kernel(const float* __restrict__ in,
                                 __hip_bfloat16* __restrict__ out, int n4) {
    int stride = gridDim.x * blockDim.x;
    for (int i = blockIdx.x * blockDim.x + threadIdx.x; i < n4; i += stride) {
        float4 v = ((const float4*)in)[i];
        bf4 o;
        o.h[0] = __float2bfloat16(v.x);
        o.h[1] = __float2bfloat16(v.y);
        o.h[2] = __float2bfloat16(v.z);
        o.h[3] = __float2bfloat16(v.w);
        ((bf4*)out)[i] = o;
    }
}

__global__ void transpose_cast_w(const float* __restrict__ W,
                                 __hip_bfloat16* __restrict__ WT, int Koff,
                                 int Cin, int Cout) {
    int total = Koff * Cin * Cout;
    int stride = gridDim.x * blockDim.x;
    for (int i = blockIdx.x * blockDim.x + threadIdx.x; i < total; i += stride) {
        int k = i / (Cin * Cout);
        int r = i - k * (Cin * Cout);
        int n = r / Cin;
        int kk = r - n * Cin;
        WT[i] = __float2bfloat16(W[((size_t)k * Cin + kk) * Cout + n]);
    }
}

__global__ void concat_b_kernel(const float* __restrict__ fb,
                                __hip_bfloat16* __restrict__ X) {
    const int total = 200000 * 32;
    int stride = gridDim.x * blockDim.x;
    for (int i = blockIdx.x * blockDim.x + threadIdx.x; i < total; i += stride) {
        int row = i >> 5;
        int c4 = (i & 31) * 4;
        float4 t = *(const float4*)(fb + (size_t)row * 128 + c4);
        bf4 o;
        o.h[0] = __float2bfloat16(t.x);
        o.h[1] = __float2bfloat16(t.y);
        o.h[2] = __float2bfloat16(t.z);
        o.h[3] = __float2bfloat16(t.w);
        *(bf4*)(X + (size_t)row * 384 + 256 + c4) = o;
    }
}

// =================== fallback path (atomic scatter, proven) ================
template <int KSTEPS>
__global__ __launch_bounds__(256) void spconv_atomic(
    const __hip_bfloat16* __restrict__ A, const __hip_bfloat16* __restrict__ BT,
    const int* __restrict__ in_map, const int* __restrict__ out_map,
    float* __restrict__ Out, int M) {
    constexpr int K = KSTEPS * 32;
    __shared__ __align__(16) char Abuf[8192];
    __shared__ __align__(16) char Bbuf[8192];
    __shared__ int om_s[128];

    const int tid = threadIdx.x;
    const int w = tid >> 6;
    const int l = tid & 63;
    const int koff = blockIdx.z;
    const int m0 = blockIdx.x * 128;
    const int n0 = blockIdx.y * 128;

    const int* im = in_map + (size_t)koff * M;
    const int* om = out_map + (size_t)koff * M;

    if (tid < 128) {
        int p = m0 + tid;
        om_s[tid] = (p < M) ? om[p] : -1;
    }

    const int rS = (w & 1) * 64 + l;
    int prow = m0 + rS;
    if (prow > M - 1) prow = M - 1;
    const __hip_bfloat16* a_row = A + (size_t)im[prow] * K;
    const __hip_bfloat16* b_row = BT + ((size_t)koff * 256 + n0 + rS) * (size_t)K;
    const int q0 = w >> 1;

    char* Al = Abuf + w * 1024 + l * 16;
    char* Bl = Bbuf + w * 1024 + l * 16;

    floatx4 acc[4][4];
#pragma unroll
    for (int i = 0; i < 4; i++)
#pragma unroll
        for (int j = 0; j < 4; j++) acc[i][j] = (floatx4)0.0f;

    const int wm = w & 1, wn = w >> 1;
    const int lm = l & 15, lq = l >> 4;

    for (int ks = 0; ks < KSTEPS; ks++) {
        const int kb = ks * 32;
        gl_lds16(a_row + kb + q0 * 8, Al);
        gl_lds16(a_row + kb + (q0 + 2) * 8, Al + 4096);
        gl_lds16(b_row + kb + q0 * 8, Bl);
        gl_lds16(b_row + kb + (q0 + 2) * 8, Bl + 4096);
        __syncthreads();

        bf16x8 af[4], bf[4];
#pragma unroll
        for (int mt = 0; mt < 4; mt++)
            af[mt] = *(const bf16x8*)(Abuf + lq * 2048 + (wm * 64 + mt * 16 + lm) * 16);
#pragma unroll
        for (int nt = 0; nt < 4; nt++)
            bf[nt] = *(const bf16x8*)(Bbuf + lq * 2048 + (wn * 64 + nt * 16 + lm) * 16);

#pragma unroll
        for (int mt = 0; mt < 4; mt++)
#pragma unroll
            for (int nt = 0; nt < 4; nt++)
                acc[mt][nt] = __builtin_amdgcn_mfma_f32_16x16x32_bf16(
                    af[mt], bf[nt], acc[mt][nt], 0, 0, 0);

        __syncthreads();
    }

#pragma unroll
    for (int mt = 0; mt < 4; mt++) {
        const int mbase = wm * 64 + mt * 16 + lq * 4;
#pragma unroll
        for (int r = 0; r < 4; r++) {
            const int orow = om_s[mbase + r];
            if (orow >= 0) {
                float* dst = Out + (size_t)orow * 256 + n0 + wn * 64 + lm;
#pragma unroll
                for (int nt = 0; nt < 4; nt++)
                    unsafeAtomicAdd(dst + nt * 16, acc[mt][nt][r]);
            }
        }
    }
}

__global__ void bn_concat_kernel(const float* __restrict__ xa,
                                 const float* __restrict__ fb,
                                 const float* __restrict__ g,
                                 const float* __restrict__ b,
                                 const float* __restrict__ mu,
                                 const float* __restrict__ var,
                                 __hip_bfloat16* __restrict__ X) {
    const int total = 200000 * 96;
    int stride = gridDim.x * blockDim.x;
    for (int i = blockIdx.x * blockDim.x + threadIdx.x; i < total; i += stride) {
        int row = i / 96;
        int c4 = (i - row * 96) * 4;
        float v[4];
        if (c4 < 256) {
            float4 t = *(const float4*)(xa + (size_t)row * 256 + c4);
            v[0] = t.x; v[1] = t.y; v[2] = t.z; v[3] = t.w;
#pragma unroll
            for (int j = 0; j < 4; j++) {
                int c = c4 + j;
                float s = g[c] * rsqrtf(var[c] + 1e-5f);
                v[j] = fmaxf((v[j] - mu[c]) * s + b[c], 0.0f);
            }
        } else {
            float4 t = *(const float4*)(fb + (size_t)row * 128 + (c4 - 256));
            v[0] = t.x; v[1] = t.y; v[2] = t.z; v[3] = t.w;
        }
        bf4 o;
#pragma unroll
        for (int j = 0; j < 4; j++) o.h[j] = __float2bfloat16(v[j]);
        *(bf4*)(X + (size_t)row * 384 + c4) = o;
    }
}

__global__ void bn_out_kernel(float* __restrict__ out, const float* __restrict__ g,
                              const float* __restrict__ b,
                              const float* __restrict__ mu,
                              const float* __restrict__ var) {
    const int total = 200000 * 64;
    int stride = gridDim.x * blockDim.x;
    for (int i = blockIdx.x * blockDim.x + threadIdx.x; i < total; i += stride) {
        int c4 = (i & 63) * 4;
        float4 t = ((const float4*)out)[i];
        float v[4] = {t.x, t.y, t.z, t.w};
#pragma unroll
        for (int j = 0; j < 4; j++) {
            int c = c4 + j;
            float s = g[c] * rsqrtf(var[c] + 1e-5f);
            v[j] = fmaxf((v[j] - mu[c]) * s + b[c], 0.0f);
        }
        ((float4*)out)[i] = make_float4(v[0], v[1], v[2], v[3]);
    }
}

// ===========================================================================
extern "C" void kernel_launch(void* const* d_in, const int* in_sizes, int n_in,
                              void* d_out, int out_size, void* d_ws,
                              size_t ws_size, hipStream_t stream) {
    const float* feats_a = (const float*)d_in[0];
    const float* feats_b = (const float*)d_in[1];
    const float* W_t = (const float*)d_in[2];
    const float* bn_t_gamma = (const float*)d_in[3];
    const float* bn_t_beta = (const float*)d_in[4];
    const float* bn_t_mean = (const float*)d_in[5];
    const float* bn_t_var = (const float*)d_in[6];
    const float* W_c = (const float*)d_in[7];
    const float* bn_c_gamma = (const float*)d_in[8];
    const float* bn_c_beta = (const float*)d_in[9];
    const float* bn_c_mean = (const float*)d_in[10];
    const float* bn_c_var = (const float*)d_in[11];
    const int* in_map_t = (const int*)d_in[12];
    const int* out_map_t = (const int*)d_in[13];
    const int* in_map_c = (const int*)d_in[14];
    const int* out_map_c = (const int*)d_in[15];
    float* out = (float*)d_out;

    // ---- workspace layout (all 256B aligned) ----
    char* ws = (char*)d_ws;
    __hip_bfloat16* a_bf = (__hip_bfloat16*)(ws + 0);            // 25,600,000
    __hip_bfloat16* wtT  = (__hip_bfloat16*)(ws + 25600000);     //  1,048,576
    __hip_bfloat16* wcT  = (__hip_bfloat16*)(ws + 26648576);     //  5,308,416
    __hip_bfloat16* x_bf = (__hip_bfloat16*)(ws + 31956992);     // 153,600,000
    unsigned* cnt   = (unsigned*)(ws + 185556992);               //    800,000
    unsigned* start = (unsigned*)(ws + 186356992);               //    800,256
    unsigned* bsum  = (unsigned*)(ws + 187157248);               //      1,024
    unsigned* cur   = (unsigned*)(ws + 187158272);               //    800,000
    unsigned* ent   = (unsigned*)(ws + 187958272);               // 12,960,000
    __hip_bfloat16* P = (__hip_bfloat16*)(ws + 200918272);
    const size_t p_avail = (ws_size > 200918272u) ? ws_size - 200918272u : 0;
    int g_c = (int)(p_avail / 61440000ull); if (g_c > 27) g_c = 27;
    int g_t = (int)(p_avail / 51200000ull); if (g_t > 8) g_t = 8;
    const bool ts_t = (g_t >= 4);
    const bool ts_c = (g_c >= 5);

    cast_bf16_kernel<<<512, 256, 0, stream>>>(feats_a, a_bf, 50000 * 256 / 4);
    transpose_cast_w<<<512, 256, 0, stream>>>(W_t, wtT, 8, 256, 256);
    transpose_cast_w<<<512, 256, 0, stream>>>(W_c, wcT, 27, 384, 256);

    // ---------------- conv_t ----------------
    if (ts_t) {
        concat_b_kernel<<<2048, 256, 0, stream>>>(feats_b, x_bf);
        hipMemsetAsync(cnt, 0, 800000, stream);
        hist_kernel<<<1024, 256, 0, stream>>>(out_map_t, 800000, cnt);
        scan1_kernel<<<196, 256, 0, stream>>>(cnt, start, bsum, 200000);
        scan2_kernel<<<1, 256, 0, stream>>>(bsum, 196);
        scan3_kernel<<<196, 256, 0, stream>>>(start, bsum, cur, 200000, 800000);
        scatter_kernel<<<1024, 256, 0, stream>>>(out_map_t, 800000, cur, ent);
        for (int q0 = 0; q0 < 8; q0 += g_t) {
            const int q1 = (q0 + g_t < 8) ? q0 + g_t : 8;
            dim3 gs(1563, 1, q1 - q0);  // ceil(100000/64)
            spconv_stage1<8><<<gs, 256, 0, stream>>>(
                a_bf, wtT + (size_t)q0 * 256 * 256, in_map_t + (size_t)q0 * 100000,
                P, 100000);
            stage2_kernel<<<50000, 256, 0, stream>>>(
                start, ent, P, q0 * 100000, q1 * 100000, out, (q0 == 0) ? 1 : 0,
                (q1 == 8) ? 1 : 0, x_bf, out, bn_t_gamma, bn_t_beta, bn_t_mean,
                bn_t_var);
        }
    } else {
        hipMemsetAsync(d_out, 0, (size_t)out_size * sizeof(float), stream);
        dim3 g1(782, 2, 8);
        spconv_atomic<8><<<g1, 256, 0, stream>>>(a_bf, wtT, in_map_t, out_map_t,
                                                 out, 100000);
        bn_concat_kernel<<<2048, 256, 0, stream>>>(out, feats_b, bn_t_gamma,
                                                   bn_t_beta, bn_t_mean, bn_t_var,
                                                   x_bf);
    }

    // ---------------- conv_c ----------------
    if (ts_c) {
        hipMemsetAsync(cnt, 0, 800000, stream);
        hist_kernel<<<1024, 256, 0, stream>>>(out_map_c, 3240000, cnt);
        scan1_kernel<<<196, 256, 0, stream>>>(cnt, start, bsum, 200000);
        scan2_kernel<<<1, 256, 0, stream>>>(bsum, 196);
        scan3_kernel<<<196, 256, 0, stream>>>(start, bsum, cur, 200000, 3240000);
        scatter_kernel<<<1024, 256, 0, stream>>>(out_map_c, 3240000, cur, ent);
        for (int q0 = 0; q0 < 27; q0 += g_c) {
            const int q1 = (q0 + g_c < 27) ? q0 + g_c : 27;
            dim3 gs(1875, 1, q1 - q0);  // 120000/64
            spconv_stage1<12><<<gs, 256, 0, stream>>>(
                x_bf, wcT + (size_t)q0 * 256 * 384, in_map_c + (size_t)q0 * 120000,
                P, 120000);
            stage2_kernel<<<50000, 256, 0, stream>>>(
                start, ent, P, q0 * 120000, q1 * 120000, out, (q0 == 0) ? 1 : 0,
                (q1 == 27) ? 2 : 0, x_bf, out, bn_c_gamma, bn_c_beta, bn_c_mean,
                bn_c_var);
        }
    } else {
        hipMemsetAsync(d_out, 0, (size_t)out_size * sizeof(float), stream);
        dim3 g2(938, 2, 27);
        spconv_atomic<12><<<g2, 256, 0, stream>>>(x_bf, wcT, in_map_c, out_map_c,
                                                  out, 120000);
        bn_out_kernel<<<2048, 256, 0, stream>>>(out, bn_c_gamma, bn_c_beta,
                                                bn_c_mean, bn_c_var);
    }
}